// Round 15
// baseline (149.686 us; speedup 1.0000x reference)
//
#include <hip/hip_runtime.h>
#include <stdint.h>
#include <math.h>

#define N_NODES 50000
#define N_EDGES 1500000
#define HDIM 128
#define TDIM 100
#define KPAD 512         // 484 padded to multiple of 32
#define BM 64            // nodes per gru block
#define NT 512           // 8 waves, wave n8 owns within-gate cols [16n8,16n8+16)
#define NBLOCKS ((N_NODES + BM - 1) / BM)   // 782
#define OPITCH 130       // output LDS stride (floats): 2-way bank alias = free

#define EQUADS (N_EDGES / 4)                    // 375000 exactly
#define SCAN_BLOCKS ((EQUADS + 255) / 256)      // 1465
#define CONV_THREADS (24576 + 2048)
#define CONV_BLOCKS ((CONV_THREADS + 255) / 256)

typedef __attribute__((ext_vector_type(8))) short short8v;
typedef __attribute__((ext_vector_type(4))) float f32x4;
typedef __attribute__((ext_vector_type(4))) unsigned int u32x4;

__device__ __forceinline__ unsigned short f2bf(float x) {
    unsigned int u = __float_as_uint(x);
    return (unsigned short)((u + 0x7fffu + ((u >> 16) & 1u)) >> 16);
}
__device__ __forceinline__ float bf2f(unsigned short b) {
    return __uint_as_float((unsigned)b << 16);
}
__device__ __forceinline__ float sigmoidf_(float x) { return 1.0f / (1.0f + __expf(-x)); }
__device__ __forceinline__ float tanhf_(float x) { return 2.0f / (1.0f + __expf(-2.0f * x)) - 1.0f; }

// Fused: blocks [0, SCAN_BLOCKS) do the edge scan (4 edges/thread, vectorized);
// blocks [SCAN_BLOCKS, SCAN_BLOCKS+CONV_BLOCKS) do the W re-layout.
__global__ void scan_convert_kernel(const int* __restrict__ dst,
                                    const float* __restrict__ edge_ts,
                                    unsigned long long* __restrict__ keys,
                                    const float* __restrict__ Wih,
                                    const float* __restrict__ Whh,
                                    unsigned short* __restrict__ wbF1,
                                    unsigned short* __restrict__ wbF2) {
    const int b = blockIdx.x;
    if (b < SCAN_BLOCKS) {
        const int t = b * 256 + threadIdx.x;      // quad index
        if (t < EQUADS) {
            const u32x4 d4 = *((const u32x4*)dst + t);
            const u32x4 t4 = *((const u32x4*)edge_ts + t);
            #pragma unroll
            for (int j = 0; j < 4; ++j) {
                const unsigned tsb = (j == 0) ? t4.x : (j == 1) ? t4.y : (j == 2) ? t4.z : t4.w;
                const int d = (int)((j == 0) ? d4.x : (j == 1) ? d4.y : (j == 2) ? d4.z : d4.w);
                // hi-word filter: hi monotone non-decreasing; 32b load can't tear.
                // tsb < hi => full key strictly loses => safe skip. Ties still atomic.
                const unsigned cur_hi = ((const unsigned*)keys)[2 * d + 1];
                if (tsb >= cur_hi) {
                    const unsigned long long key =
                        ((unsigned long long)tsb << 32) | (unsigned int)(4 * t + j + 1);
                    atomicMax(&keys[d], key);
                }
            }
        }
        return;
    }
    // ---- W re-layout: frag-major, 8-way N-split, W_hh folded into r,z gates
    // (m_bar[128:256] == mem_s, so W' = W_ih + shift(W_hh) is exact) ----
    const int t = (b - SCAN_BLOCKS) * 256 + threadIdx.x;
    if (t < 24576) {
        const int bb = t >> 10, kt = (t >> 6) & 15, l = t & 63;
        const int g3 = bb >> 3, n8 = bb & 7;
        const int row = g3 * 128 + n8 * 16 + (l & 15);
        const int scol = kt * 32 + (l >> 4) * 8;
        unsigned short v[8];
        #pragma unroll
        for (int j = 0; j < 8; ++j) {
            const int k = scol + j;
            float w = (k < 484) ? Wih[row * 484 + k] : 0.f;
            if (g3 < 2 && k >= 128 && k < 256) w += Whh[row * 128 + (k - 128)];
            v[j] = f2bf(w);
        }
        uint4 pk;
        pk.x = (unsigned)v[0] | ((unsigned)v[1] << 16);
        pk.y = (unsigned)v[2] | ((unsigned)v[3] << 16);
        pk.z = (unsigned)v[4] | ((unsigned)v[5] << 16);
        pk.w = (unsigned)v[6] | ((unsigned)v[7] << 16);
        *(uint4*)&wbF1[(size_t)t * 8] = pk;
    } else if (t < CONV_THREADS) {
        const int t2 = t - 24576;
        const int n8 = t2 >> 8, kt = (t2 >> 6) & 3, l = t2 & 63;
        const int row = 256 + n8 * 16 + (l & 15);
        const int scol = kt * 32 + (l >> 4) * 8;
        unsigned short v[8];
        #pragma unroll
        for (int j = 0; j < 8; ++j) v[j] = f2bf(Whh[row * 128 + scol + j]);
        uint4 pk;
        pk.x = (unsigned)v[0] | ((unsigned)v[1] << 16);
        pk.y = (unsigned)v[2] | ((unsigned)v[3] << 16);
        pk.z = (unsigned)v[4] | ((unsigned)v[5] << 16);
        pk.w = (unsigned)v[6] | ((unsigned)v[7] << 16);
        *(uint4*)&wbF2[(size_t)t2 * 8] = pk;
    }
}

__global__ __launch_bounds__(NT, 4)
void gru_mfma_kernel(const int* __restrict__ src,
                     const float* __restrict__ edge_ts,
                     const float* __restrict__ ef,
                     const float* __restrict__ mem,
                     const float* __restrict__ lut,
                     const float* __restrict__ tw,
                     const float* __restrict__ tb,
                     const float* __restrict__ bih,
                     const float* __restrict__ bhh,
                     const unsigned short* __restrict__ wbF1,
                     const unsigned short* __restrict__ wbF2,
                     const unsigned long long* __restrict__ keys,
                     float* __restrict__ out) {
    __shared__ unsigned short Alds[BM * KPAD];   // 64 KB -> 2 blocks/CU
    __shared__ unsigned char sh_has[BM];
    const int tid = threadIdx.x;
    const int base = blockIdx.x * BM;

    // ---- staging: 8 threads per node (bf16, XOR-swizzled rows) ----
    {
        const int i = tid >> 3, l8 = tid & 7;
        const int n = base + i;
        if (n < N_NODES) {
            unsigned long long key = keys[n];
            const int has = (key != 0ULL);
            const int e = has ? (int)((unsigned)key - 1u) : 0;
            const int s = src[e];
            const float tv = edge_ts[e];
            const float d = tv - lut[s];
            if (l8 == 0) {
                sh_has[i] = (unsigned char)has;
                out[(size_t)N_NODES * HDIM + n] = has ? tv : lut[n];
            }
            const int swg = i & 7;
            unsigned short* Arow = &Alds[i * KPAD];
            #pragma unroll
            for (int p = 0; p < 8; ++p) {
                const int gk = p * 8 + l8, k0 = gk * 8;   // 16B group 0..63
                float f[8];
                if (k0 < 384) {
                    const float* sp = (k0 < 128) ? mem + (size_t)s * HDIM + k0
                                    : (k0 < 256) ? mem + (size_t)n * HDIM + (k0 - 128)
                                                 : ef + (size_t)e * HDIM + (k0 - 256);
                    u32x4 w0 = __builtin_nontemporal_load((const u32x4*)sp);
                    u32x4 w1 = __builtin_nontemporal_load((const u32x4*)sp + 1);
                    f[0]=__uint_as_float(w0.x); f[1]=__uint_as_float(w0.y);
                    f[2]=__uint_as_float(w0.z); f[3]=__uint_as_float(w0.w);
                    f[4]=__uint_as_float(w1.x); f[5]=__uint_as_float(w1.y);
                    f[6]=__uint_as_float(w1.z); f[7]=__uint_as_float(w1.w);
                } else {
                    #pragma unroll
                    for (int j2 = 0; j2 < 8; ++j2) {
                        int q = k0 - 384 + j2;
                        f[j2] = (q < TDIM) ? cosf(fmaf(d, tw[q], tb[q])) : 0.f;
                    }
                }
                uint4 pk;
                pk.x = (unsigned)f2bf(f[0]) | ((unsigned)f2bf(f[1]) << 16);
                pk.y = (unsigned)f2bf(f[2]) | ((unsigned)f2bf(f[3]) << 16);
                pk.z = (unsigned)f2bf(f[4]) | ((unsigned)f2bf(f[5]) << 16);
                pk.w = (unsigned)f2bf(f[6]) | ((unsigned)f2bf(f[7]) << 16);
                *(uint4*)&Arow[(size_t)(gk ^ swg) * 8] = pk;
            }
        }
    }
    __syncthreads();

    // ---- MFMA GEMM: wave n8 owns within-gate cols [16n8,16n8+16), all 64 rows ----
    const int n8 = tid >> 6, l = tid & 63;
    const int lr = l & 15, lh = l >> 4;

    const short8v* Bv1 = (const short8v*)wbF1 + l;
    const short8v* Bv2 = (const short8v*)wbF2 + l;

    const f32x4 fzero = {0.f, 0.f, 0.f, 0.f};
    f32x4 acc[4][4];  // [plane r,z,i_n,h_n][mf]
    #pragma unroll
    for (int q = 0; q < 4; ++q)
        #pragma unroll
        for (int mf = 0; mf < 4; ++mf) acc[q][mf] = fzero;

    // GEMM1: r,z (W_hh folded -> complete) + i_n over K=512
    #pragma unroll 2
    for (int kt = 0; kt < 16; ++kt) {
        short8v b[3];
        #pragma unroll
        for (int g3 = 0; g3 < 3; ++g3)
            b[g3] = Bv1[((g3 * 8 + n8) * 16 + kt) * 64];
        short8v a[4];
        #pragma unroll
        for (int mf = 0; mf < 4; ++mf) {
            const int row = mf * 16 + lr;
            a[mf] = *(const short8v*)&Alds[row * KPAD + ((kt * 32 + lh * 8) ^ ((row & 7) << 3))];
        }
        #pragma unroll
        for (int g3 = 0; g3 < 3; ++g3)
            #pragma unroll
            for (int mf = 0; mf < 4; ++mf)
                acc[g3][mf] = __builtin_amdgcn_mfma_f32_16x16x32_bf16(
                    a[mf], b[g3], acc[g3][mf], 0, 0, 0);
    }
    // GEMM2: h_n plane only (A k-slice 128..256)
    #pragma unroll
    for (int kt = 0; kt < 4; ++kt) {
        short8v b2 = Bv2[(n8 * 4 + kt) * 64];
        short8v a[4];
        #pragma unroll
        for (int mf = 0; mf < 4; ++mf) {
            const int row = mf * 16 + lr;
            a[mf] = *(const short8v*)&Alds[row * KPAD + (((128 + kt * 32) + lh * 8) ^ ((row & 7) << 3))];
        }
        #pragma unroll
        for (int mf = 0; mf < 4; ++mf)
            acc[3][mf] = __builtin_amdgcn_mfma_f32_16x16x32_bf16(
                a[mf], b2, acc[3][mf], 0, 0, 0);
    }

    // ---- epilogue: compute o in regs (h from LDS), LDS-stage, coalesced stores ----
    const int c = n8 * 16 + lr;
    const float br = bih[c] + bhh[c];
    const float bz = bih[HDIM + c] + bhh[HDIM + c];
    const float bin = bih[2 * HDIM + c];
    const float bhn = bhh[2 * HDIM + c];
    const int hg = 16 + (c >> 3);        // 16B-group of element 128+c
    const int ho = c & 7;
    float o[4][4];
    #pragma unroll
    for (int mf = 0; mf < 4; ++mf)
        #pragma unroll
        for (int ii = 0; ii < 4; ++ii) {
            const int row = mf * 16 + lh * 4 + ii;
            const float h = bf2f(Alds[row * KPAD + (hg ^ (row & 7)) * 8 + ho]);
            const float r = sigmoidf_(acc[0][mf][ii] + br);
            const float z = sigmoidf_(acc[1][mf][ii] + bz);
            const float ng = tanhf_(acc[2][mf][ii] + bin + r * (acc[3][mf][ii] + bhn));
            o[mf][ii] = sh_has[row] ? (1.f - z) * ng + z * h : h;
        }
    __syncthreads();                      // all A/h reads done -> safe to reuse LDS
    float* o_lds = (float*)Alds;          // [64][OPITCH] = 33280 B, fits in Alds
    #pragma unroll
    for (int mf = 0; mf < 4; ++mf)
        #pragma unroll
        for (int ii = 0; ii < 4; ++ii) {
            const int row = mf * 16 + lh * 4 + ii;
            o_lds[row * OPITCH + c] = o[mf][ii];
        }
    __syncthreads();
    const int nvalid = (N_NODES - base < BM) ? (N_NODES - base) : BM;
    #pragma unroll
    for (int sw = 0; sw < 4; ++sw) {
        const int idx = sw * 2048 + tid * 4;      // float index in 64x128 tile
        const int row = idx >> 7, col = idx & 127;
        if (row < nvalid) {
            const float4 v = *(const float4*)&o_lds[row * OPITCH + col];
            *(float4*)&out[(size_t)(base + row) * HDIM + col] = v;
        }
    }
}

extern "C" void kernel_launch(void* const* d_in, const int* in_sizes, int n_in,
                              void* d_out, int out_size, void* d_ws, size_t ws_size,
                              hipStream_t stream) {
    const int* src       = (const int*)d_in[0];
    const int* dst       = (const int*)d_in[1];
    const float* edge_ts = (const float*)d_in[2];
    const float* ef      = (const float*)d_in[3];
    const float* mem     = (const float*)d_in[4];
    const float* lut     = (const float*)d_in[5];
    const float* tw      = (const float*)d_in[6];
    const float* tb      = (const float*)d_in[7];
    const float* Wih     = (const float*)d_in[8];
    const float* Whh     = (const float*)d_in[9];
    const float* bih     = (const float*)d_in[10];
    const float* bhh     = (const float*)d_in[11];
    float* out = (float*)d_out;

    char* ws = (char*)d_ws;
    unsigned long long* keys = (unsigned long long*)ws;      // 400000 B (region 512K)
    unsigned short* wbF1 = (unsigned short*)(ws + 524288);   // 393216 B
    unsigned short* wbF2 = (unsigned short*)(ws + 917504);   //  32768 B

    hipMemsetAsync(keys, 0, (size_t)N_NODES * 8, stream);
    scan_convert_kernel<<<SCAN_BLOCKS + CONV_BLOCKS, 256, 0, stream>>>(
        dst, edge_ts, keys, Wih, Whh, wbF1, wbF2);
    gru_mfma_kernel<<<NBLOCKS, NT, 0, stream>>>(
        src, edge_ts, ef, mem, lut, tw, tb, bih, bhh, wbF1, wbF2, keys, out);
}

// Round 16
// 125.343 us; speedup vs baseline: 1.1942x; 1.1942x over previous
//
#include <hip/hip_runtime.h>
#include <stdint.h>
#include <math.h>

#define N_NODES 50000
#define N_EDGES 1500000
#define HDIM 128
#define TDIM 100
#define KPAD 512         // 484 padded to multiple of 32
#define BM 64            // nodes per gru block
#define NT 512           // 8 waves, wave n8 owns within-gate cols [16n8,16n8+16)
#define NBLOCKS ((N_NODES + BM - 1) / BM)   // 782
#define OPITCH 130       // output LDS stride (floats): 2-way bank alias = free

#define KEYS_QUADS 25000                        // 50000 u64 = 25000 x 16B
#define KEYS_BLOCKS ((KEYS_QUADS + 255) / 256)  // 98
#define CONV_THREADS (24576 + 2048)
#define CONV_BLOCKS ((CONV_THREADS + 255) / 256)

typedef __attribute__((ext_vector_type(8))) short short8v;
typedef __attribute__((ext_vector_type(4))) float f32x4;
typedef __attribute__((ext_vector_type(4))) unsigned int u32x4;

__device__ __forceinline__ unsigned short f2bf(float x) {
    unsigned int u = __float_as_uint(x);
    return (unsigned short)((u + 0x7fffu + ((u >> 16) & 1u)) >> 16);
}
__device__ __forceinline__ float bf2f(unsigned short b) {
    return __uint_as_float((unsigned)b << 16);
}
__device__ __forceinline__ float sigmoidf_(float x) { return 1.0f / (1.0f + __expf(-x)); }
__device__ __forceinline__ float tanhf_(float x) { return 2.0f / (1.0f + __expf(-2.0f * x)) - 1.0f; }

// Fused init+convert (independent of scan; launched FIRST):
// blocks [0, KEYS_BLOCKS): zero the keys array.
// blocks [KEYS_BLOCKS, ...): frag-major W re-layout, 8-way N-split, with W_hh
// FOLDED into W_ih for the r,z gates (m_bar[128:256] == mem_s -> exact).
__global__ void init_convert_kernel(unsigned long long* __restrict__ keys,
                                    const float* __restrict__ Wih,
                                    const float* __restrict__ Whh,
                                    unsigned short* __restrict__ wbF1,
                                    unsigned short* __restrict__ wbF2) {
    const int b = blockIdx.x;
    if (b < KEYS_BLOCKS) {
        const int t = b * 256 + threadIdx.x;
        if (t < KEYS_QUADS) ((u32x4*)keys)[t] = (u32x4){0u, 0u, 0u, 0u};
        return;
    }
    const int t = (b - KEYS_BLOCKS) * 256 + threadIdx.x;
    if (t < 24576) {
        const int bb = t >> 10, kt = (t >> 6) & 15, l = t & 63;
        const int g3 = bb >> 3, n8 = bb & 7;
        const int row = g3 * 128 + n8 * 16 + (l & 15);
        const int scol = kt * 32 + (l >> 4) * 8;
        unsigned short v[8];
        #pragma unroll
        for (int j = 0; j < 8; ++j) {
            const int k = scol + j;
            float w = (k < 484) ? Wih[row * 484 + k] : 0.f;
            if (g3 < 2 && k >= 128 && k < 256) w += Whh[row * 128 + (k - 128)];
            v[j] = f2bf(w);
        }
        uint4 pk;
        pk.x = (unsigned)v[0] | ((unsigned)v[1] << 16);
        pk.y = (unsigned)v[2] | ((unsigned)v[3] << 16);
        pk.z = (unsigned)v[4] | ((unsigned)v[5] << 16);
        pk.w = (unsigned)v[6] | ((unsigned)v[7] << 16);
        *(uint4*)&wbF1[(size_t)t * 8] = pk;
    } else if (t < CONV_THREADS) {
        const int t2 = t - 24576;
        const int n8 = t2 >> 8, kt = (t2 >> 6) & 3, l = t2 & 63;
        const int row = 256 + n8 * 16 + (l & 15);
        const int scol = kt * 32 + (l >> 4) * 8;
        unsigned short v[8];
        #pragma unroll
        for (int j = 0; j < 8; ++j) v[j] = f2bf(Whh[row * 128 + scol + j]);
        uint4 pk;
        pk.x = (unsigned)v[0] | ((unsigned)v[1] << 16);
        pk.y = (unsigned)v[2] | ((unsigned)v[3] << 16);
        pk.z = (unsigned)v[4] | ((unsigned)v[5] << 16);
        pk.w = (unsigned)v[6] | ((unsigned)v[7] << 16);
        *(uint4*)&wbF2[(size_t)t2 * 8] = pk;
    }
}

// R14 scan: 1 edge/thread (max TLP for the atomic/filter chain — R15 showed
// 4-edge serialization costs ~20 us).
__global__ void scan_edges_kernel(const int* __restrict__ dst,
                                  const float* __restrict__ edge_ts,
                                  unsigned long long* __restrict__ keys) {
    int e = blockIdx.x * 256 + threadIdx.x;
    if (e < N_EDGES) {
        unsigned tsb = __float_as_uint(__builtin_nontemporal_load(&edge_ts[e]));
        int d = __builtin_nontemporal_load(&dst[e]);
        // hi-word filter: hi monotone non-decreasing; 32b load can't tear.
        // tsb < hi => full key strictly loses => safe skip. Ties still atomic.
        unsigned cur_hi = ((const unsigned*)keys)[2 * d + 1];
        if (tsb >= cur_hi) {
            unsigned long long key =
                ((unsigned long long)tsb << 32) | (unsigned int)(e + 1);
            atomicMax(&keys[d], key);
        }
    }
}

__global__ __launch_bounds__(NT, 4)
void gru_mfma_kernel(const int* __restrict__ src,
                     const float* __restrict__ edge_ts,
                     const float* __restrict__ ef,
                     const float* __restrict__ mem,
                     const float* __restrict__ lut,
                     const float* __restrict__ tw,
                     const float* __restrict__ tb,
                     const float* __restrict__ bih,
                     const float* __restrict__ bhh,
                     const unsigned short* __restrict__ wbF1,
                     const unsigned short* __restrict__ wbF2,
                     const unsigned long long* __restrict__ keys,
                     float* __restrict__ out) {
    __shared__ unsigned short Alds[BM * KPAD];   // 64 KB -> 2 blocks/CU
    __shared__ unsigned char sh_has[BM];
    const int tid = threadIdx.x;
    const int base = blockIdx.x * BM;

    // ---- staging: 8 threads per node (bf16, XOR-swizzled rows) ----
    {
        const int i = tid >> 3, l8 = tid & 7;
        const int n = base + i;
        if (n < N_NODES) {
            unsigned long long key = keys[n];
            const int has = (key != 0ULL);
            const int e = has ? (int)((unsigned)key - 1u) : 0;
            const int s = src[e];
            const float tv = edge_ts[e];
            const float d = tv - lut[s];
            if (l8 == 0) {
                sh_has[i] = (unsigned char)has;
                out[(size_t)N_NODES * HDIM + n] = has ? tv : lut[n];
            }
            const int swg = i & 7;
            unsigned short* Arow = &Alds[i * KPAD];
            #pragma unroll
            for (int p = 0; p < 8; ++p) {
                const int gk = p * 8 + l8, k0 = gk * 8;   // 16B group 0..63
                float f[8];
                if (k0 < 384) {
                    const float* sp = (k0 < 128) ? mem + (size_t)s * HDIM + k0
                                    : (k0 < 256) ? mem + (size_t)n * HDIM + (k0 - 128)
                                                 : ef + (size_t)e * HDIM + (k0 - 256);
                    u32x4 w0 = __builtin_nontemporal_load((const u32x4*)sp);
                    u32x4 w1 = __builtin_nontemporal_load((const u32x4*)sp + 1);
                    f[0]=__uint_as_float(w0.x); f[1]=__uint_as_float(w0.y);
                    f[2]=__uint_as_float(w0.z); f[3]=__uint_as_float(w0.w);
                    f[4]=__uint_as_float(w1.x); f[5]=__uint_as_float(w1.y);
                    f[6]=__uint_as_float(w1.z); f[7]=__uint_as_float(w1.w);
                } else {
                    #pragma unroll
                    for (int j2 = 0; j2 < 8; ++j2) {
                        int q = k0 - 384 + j2;
                        f[j2] = (q < TDIM) ? cosf(fmaf(d, tw[q], tb[q])) : 0.f;
                    }
                }
                uint4 pk;
                pk.x = (unsigned)f2bf(f[0]) | ((unsigned)f2bf(f[1]) << 16);
                pk.y = (unsigned)f2bf(f[2]) | ((unsigned)f2bf(f[3]) << 16);
                pk.z = (unsigned)f2bf(f[4]) | ((unsigned)f2bf(f[5]) << 16);
                pk.w = (unsigned)f2bf(f[6]) | ((unsigned)f2bf(f[7]) << 16);
                *(uint4*)&Arow[(size_t)(gk ^ swg) * 8] = pk;
            }
        }
    }
    __syncthreads();

    // ---- MFMA GEMM: wave n8 owns within-gate cols [16n8,16n8+16), all 64 rows ----
    const int n8 = tid >> 6, l = tid & 63;
    const int lr = l & 15, lh = l >> 4;

    const short8v* Bv1 = (const short8v*)wbF1 + l;
    const short8v* Bv2 = (const short8v*)wbF2 + l;

    const f32x4 fzero = {0.f, 0.f, 0.f, 0.f};
    f32x4 acc[4][4];  // [plane r,z,i_n,h_n][mf]
    #pragma unroll
    for (int q = 0; q < 4; ++q)
        #pragma unroll
        for (int mf = 0; mf < 4; ++mf) acc[q][mf] = fzero;

    // GEMM1: r,z (W_hh folded -> complete) + i_n over K=512
    #pragma unroll 2
    for (int kt = 0; kt < 16; ++kt) {
        short8v b[3];
        #pragma unroll
        for (int g3 = 0; g3 < 3; ++g3)
            b[g3] = Bv1[((g3 * 8 + n8) * 16 + kt) * 64];
        short8v a[4];
        #pragma unroll
        for (int mf = 0; mf < 4; ++mf) {
            const int row = mf * 16 + lr;
            a[mf] = *(const short8v*)&Alds[row * KPAD + ((kt * 32 + lh * 8) ^ ((row & 7) << 3))];
        }
        #pragma unroll
        for (int g3 = 0; g3 < 3; ++g3)
            #pragma unroll
            for (int mf = 0; mf < 4; ++mf)
                acc[g3][mf] = __builtin_amdgcn_mfma_f32_16x16x32_bf16(
                    a[mf], b[g3], acc[g3][mf], 0, 0, 0);
    }
    // GEMM2: h_n plane only (A k-slice 128..256)
    #pragma unroll
    for (int kt = 0; kt < 4; ++kt) {
        short8v b2 = Bv2[(n8 * 4 + kt) * 64];
        short8v a[4];
        #pragma unroll
        for (int mf = 0; mf < 4; ++mf) {
            const int row = mf * 16 + lr;
            a[mf] = *(const short8v*)&Alds[row * KPAD + (((128 + kt * 32) + lh * 8) ^ ((row & 7) << 3))];
        }
        #pragma unroll
        for (int mf = 0; mf < 4; ++mf)
            acc[3][mf] = __builtin_amdgcn_mfma_f32_16x16x32_bf16(
                a[mf], b2, acc[3][mf], 0, 0, 0);
    }

    // ---- epilogue: compute o in regs (h from LDS), LDS-stage, coalesced stores ----
    const int c = n8 * 16 + lr;
    const float br = bih[c] + bhh[c];
    const float bz = bih[HDIM + c] + bhh[HDIM + c];
    const float bin = bih[2 * HDIM + c];
    const float bhn = bhh[2 * HDIM + c];
    const int hg = 16 + (c >> 3);        // 16B-group of element 128+c
    const int ho = c & 7;
    float o[4][4];
    #pragma unroll
    for (int mf = 0; mf < 4; ++mf)
        #pragma unroll
        for (int ii = 0; ii < 4; ++ii) {
            const int row = mf * 16 + lh * 4 + ii;
            const float h = bf2f(Alds[row * KPAD + (hg ^ (row & 7)) * 8 + ho]);
            const float r = sigmoidf_(acc[0][mf][ii] + br);
            const float z = sigmoidf_(acc[1][mf][ii] + bz);
            const float ng = tanhf_(acc[2][mf][ii] + bin + r * (acc[3][mf][ii] + bhn));
            o[mf][ii] = sh_has[row] ? (1.f - z) * ng + z * h : h;
        }
    __syncthreads();                      // all A/h reads done -> safe to reuse LDS
    float* o_lds = (float*)Alds;          // [64][OPITCH] = 33280 B, fits in Alds
    #pragma unroll
    for (int mf = 0; mf < 4; ++mf)
        #pragma unroll
        for (int ii = 0; ii < 4; ++ii) {
            const int row = mf * 16 + lh * 4 + ii;
            o_lds[row * OPITCH + c] = o[mf][ii];
        }
    __syncthreads();
    const int nvalid = (N_NODES - base < BM) ? (N_NODES - base) : BM;
    #pragma unroll
    for (int sw = 0; sw < 4; ++sw) {
        const int idx = sw * 2048 + tid * 4;      // float index in 64x128 tile
        const int row = idx >> 7, col = idx & 127;
        if (row < nvalid) {
            const float4 v = *(const float4*)&o_lds[row * OPITCH + col];
            *(float4*)&out[(size_t)(base + row) * HDIM + col] = v;
        }
    }
}

extern "C" void kernel_launch(void* const* d_in, const int* in_sizes, int n_in,
                              void* d_out, int out_size, void* d_ws, size_t ws_size,
                              hipStream_t stream) {
    const int* src       = (const int*)d_in[0];
    const int* dst       = (const int*)d_in[1];
    const float* edge_ts = (const float*)d_in[2];
    const float* ef      = (const float*)d_in[3];
    const float* mem     = (const float*)d_in[4];
    const float* lut     = (const float*)d_in[5];
    const float* tw      = (const float*)d_in[6];
    const float* tb      = (const float*)d_in[7];
    const float* Wih     = (const float*)d_in[8];
    const float* Whh     = (const float*)d_in[9];
    const float* bih     = (const float*)d_in[10];
    const float* bhh     = (const float*)d_in[11];
    float* out = (float*)d_out;

    char* ws = (char*)d_ws;
    unsigned long long* keys = (unsigned long long*)ws;      // 400000 B (region 512K)
    unsigned short* wbF1 = (unsigned short*)(ws + 524288);   // 393216 B
    unsigned short* wbF2 = (unsigned short*)(ws + 917504);   //  32768 B

    init_convert_kernel<<<KEYS_BLOCKS + CONV_BLOCKS, 256, 0, stream>>>(
        keys, Wih, Whh, wbF1, wbF2);
    scan_edges_kernel<<<(N_EDGES + 255) / 256, 256, 0, stream>>>(dst, edge_ts, keys);
    gru_mfma_kernel<<<NBLOCKS, NT, 0, stream>>>(
        src, edge_ts, ef, mem, lut, tw, tb, bih, bhh, wbF1, wbF2, keys, out);
}

// Round 17
// 125.109 us; speedup vs baseline: 1.1964x; 1.0019x over previous
//
#include <hip/hip_runtime.h>
#include <stdint.h>
#include <math.h>

#define N_NODES 50000
#define N_EDGES 1500000
#define HDIM 128
#define TDIM 100
#define KPAD 512         // 484 padded to multiple of 32
#define BM 64            // nodes per gru block
#define NT 512           // 8 waves, wave n8 owns within-gate cols [16n8,16n8+16)
#define NBLOCKS ((N_NODES + BM - 1) / BM)   // 782
#define OPITCH 130       // output LDS stride (floats): 2-way bank alias = free

#define KEYS_QUADS 25000                        // 50000 u64 = 25000 x 16B
#define KEYS_BLOCKS ((KEYS_QUADS + 255) / 256)  // 98
#define CONV_THREADS (24576 + 2048)
#define CONV_BLOCKS ((CONV_THREADS + 255) / 256)

typedef __attribute__((ext_vector_type(8))) short short8v;
typedef __attribute__((ext_vector_type(4))) float f32x4;
typedef __attribute__((ext_vector_type(4))) unsigned int u32x4;

__device__ __forceinline__ unsigned short f2bf(float x) {
    unsigned int u = __float_as_uint(x);
    return (unsigned short)((u + 0x7fffu + ((u >> 16) & 1u)) >> 16);
}
__device__ __forceinline__ float bf2f(unsigned short b) {
    return __uint_as_float((unsigned)b << 16);
}
__device__ __forceinline__ float sigmoidf_(float x) { return 1.0f / (1.0f + __expf(-x)); }
__device__ __forceinline__ float tanhf_(float x) { return 2.0f / (1.0f + __expf(-2.0f * x)) - 1.0f; }

// Fused init+convert (independent of scan; launched FIRST):
// blocks [0, KEYS_BLOCKS): zero the keys array.
// blocks [KEYS_BLOCKS, ...): frag-major W re-layout, 8-way N-split, with W_hh
// FOLDED into W_ih for the r,z gates (m_bar[128:256] == mem_s -> exact).
__global__ void init_convert_kernel(unsigned long long* __restrict__ keys,
                                    const float* __restrict__ Wih,
                                    const float* __restrict__ Whh,
                                    unsigned short* __restrict__ wbF1,
                                    unsigned short* __restrict__ wbF2) {
    const int b = blockIdx.x;
    if (b < KEYS_BLOCKS) {
        const int t = b * 256 + threadIdx.x;
        if (t < KEYS_QUADS) ((u32x4*)keys)[t] = (u32x4){0u, 0u, 0u, 0u};
        return;
    }
    const int t = (b - KEYS_BLOCKS) * 256 + threadIdx.x;
    if (t < 24576) {
        const int bb = t >> 10, kt = (t >> 6) & 15, l = t & 63;
        const int g3 = bb >> 3, n8 = bb & 7;
        const int row = g3 * 128 + n8 * 16 + (l & 15);
        const int scol = kt * 32 + (l >> 4) * 8;
        unsigned short v[8];
        #pragma unroll
        for (int j = 0; j < 8; ++j) {
            const int k = scol + j;
            float w = (k < 484) ? Wih[row * 484 + k] : 0.f;
            if (g3 < 2 && k >= 128 && k < 256) w += Whh[row * 128 + (k - 128)];
            v[j] = f2bf(w);
        }
        uint4 pk;
        pk.x = (unsigned)v[0] | ((unsigned)v[1] << 16);
        pk.y = (unsigned)v[2] | ((unsigned)v[3] << 16);
        pk.z = (unsigned)v[4] | ((unsigned)v[5] << 16);
        pk.w = (unsigned)v[6] | ((unsigned)v[7] << 16);
        *(uint4*)&wbF1[(size_t)t * 8] = pk;
    } else if (t < CONV_THREADS) {
        const int t2 = t - 24576;
        const int n8 = t2 >> 8, kt = (t2 >> 6) & 3, l = t2 & 63;
        const int row = 256 + n8 * 16 + (l & 15);
        const int scol = kt * 32 + (l >> 4) * 8;
        unsigned short v[8];
        #pragma unroll
        for (int j = 0; j < 8; ++j) v[j] = f2bf(Whh[row * 128 + scol + j]);
        uint4 pk;
        pk.x = (unsigned)v[0] | ((unsigned)v[1] << 16);
        pk.y = (unsigned)v[2] | ((unsigned)v[3] << 16);
        pk.z = (unsigned)v[4] | ((unsigned)v[5] << 16);
        pk.w = (unsigned)v[6] | ((unsigned)v[7] << 16);
        *(uint4*)&wbF2[(size_t)t2 * 8] = pk;
    }
}

// Scan: 1 edge/thread (max TLP for the atomic/filter chain — R15 showed
// 4-edge serialization costs ~20 us).
__global__ void scan_edges_kernel(const int* __restrict__ dst,
                                  const float* __restrict__ edge_ts,
                                  unsigned long long* __restrict__ keys) {
    int e = blockIdx.x * 256 + threadIdx.x;
    if (e < N_EDGES) {
        unsigned tsb = __float_as_uint(__builtin_nontemporal_load(&edge_ts[e]));
        int d = __builtin_nontemporal_load(&dst[e]);
        // hi-word filter: hi monotone non-decreasing; 32b load can't tear.
        // tsb < hi => full key strictly loses => safe skip. Ties still atomic.
        unsigned cur_hi = ((const unsigned*)keys)[2 * d + 1];
        if (tsb >= cur_hi) {
            unsigned long long key =
                ((unsigned long long)tsb << 32) | (unsigned int)(e + 1);
            atomicMax(&keys[d], key);
        }
    }
}

// __launch_bounds__(NT, 2): occupancy is LDS-limited to 2 blocks/CU (= 4
// waves/EU) regardless, so min-waves=4 only capped the register allocator
// at 128 (R11 PMC: VGPR_Count=64 arch + 64 AGPR acc = pinned at cap).
// min-waves=2 -> 256-reg cap -> allocator can pipeline the B-stream.
__global__ __launch_bounds__(NT, 2)
void gru_mfma_kernel(const int* __restrict__ src,
                     const float* __restrict__ edge_ts,
                     const float* __restrict__ ef,
                     const float* __restrict__ mem,
                     const float* __restrict__ lut,
                     const float* __restrict__ tw,
                     const float* __restrict__ tb,
                     const float* __restrict__ bih,
                     const float* __restrict__ bhh,
                     const unsigned short* __restrict__ wbF1,
                     const unsigned short* __restrict__ wbF2,
                     const unsigned long long* __restrict__ keys,
                     float* __restrict__ out) {
    __shared__ unsigned short Alds[BM * KPAD];   // 64 KB -> 2 blocks/CU
    __shared__ unsigned char sh_has[BM];
    const int tid = threadIdx.x;
    const int base = blockIdx.x * BM;

    // ---- staging: 8 threads per node (bf16, XOR-swizzled rows) ----
    {
        const int i = tid >> 3, l8 = tid & 7;
        const int n = base + i;
        if (n < N_NODES) {
            unsigned long long key = keys[n];
            const int has = (key != 0ULL);
            const int e = has ? (int)((unsigned)key - 1u) : 0;
            const int s = src[e];
            const float tv = edge_ts[e];
            const float d = tv - lut[s];
            if (l8 == 0) {
                sh_has[i] = (unsigned char)has;
                out[(size_t)N_NODES * HDIM + n] = has ? tv : lut[n];
            }
            const int swg = i & 7;
            unsigned short* Arow = &Alds[i * KPAD];
            #pragma unroll
            for (int p = 0; p < 8; ++p) {
                const int gk = p * 8 + l8, k0 = gk * 8;   // 16B group 0..63
                float f[8];
                if (k0 < 384) {
                    const float* sp = (k0 < 128) ? mem + (size_t)s * HDIM + k0
                                    : (k0 < 256) ? mem + (size_t)n * HDIM + (k0 - 128)
                                                 : ef + (size_t)e * HDIM + (k0 - 256);
                    u32x4 w0 = __builtin_nontemporal_load((const u32x4*)sp);
                    u32x4 w1 = __builtin_nontemporal_load((const u32x4*)sp + 1);
                    f[0]=__uint_as_float(w0.x); f[1]=__uint_as_float(w0.y);
                    f[2]=__uint_as_float(w0.z); f[3]=__uint_as_float(w0.w);
                    f[4]=__uint_as_float(w1.x); f[5]=__uint_as_float(w1.y);
                    f[6]=__uint_as_float(w1.z); f[7]=__uint_as_float(w1.w);
                } else {
                    #pragma unroll
                    for (int j2 = 0; j2 < 8; ++j2) {
                        int q = k0 - 384 + j2;
                        f[j2] = (q < TDIM) ? cosf(fmaf(d, tw[q], tb[q])) : 0.f;
                    }
                }
                uint4 pk;
                pk.x = (unsigned)f2bf(f[0]) | ((unsigned)f2bf(f[1]) << 16);
                pk.y = (unsigned)f2bf(f[2]) | ((unsigned)f2bf(f[3]) << 16);
                pk.z = (unsigned)f2bf(f[4]) | ((unsigned)f2bf(f[5]) << 16);
                pk.w = (unsigned)f2bf(f[6]) | ((unsigned)f2bf(f[7]) << 16);
                *(uint4*)&Arow[(size_t)(gk ^ swg) * 8] = pk;
            }
        }
    }
    __syncthreads();

    // ---- MFMA GEMM: wave n8 owns within-gate cols [16n8,16n8+16), all 64 rows ----
    const int n8 = tid >> 6, l = tid & 63;
    const int lr = l & 15, lh = l >> 4;

    const short8v* Bv1 = (const short8v*)wbF1 + l;
    const short8v* Bv2 = (const short8v*)wbF2 + l;

    const f32x4 fzero = {0.f, 0.f, 0.f, 0.f};
    f32x4 acc[4][4];  // [plane r,z,i_n,h_n][mf]
    #pragma unroll
    for (int q = 0; q < 4; ++q)
        #pragma unroll
        for (int mf = 0; mf < 4; ++mf) acc[q][mf] = fzero;

    // GEMM1: r,z (W_hh folded -> complete) + i_n over K=512
    #pragma unroll 2
    for (int kt = 0; kt < 16; ++kt) {
        short8v b[3];
        #pragma unroll
        for (int g3 = 0; g3 < 3; ++g3)
            b[g3] = Bv1[((g3 * 8 + n8) * 16 + kt) * 64];
        short8v a[4];
        #pragma unroll
        for (int mf = 0; mf < 4; ++mf) {
            const int row = mf * 16 + lr;
            a[mf] = *(const short8v*)&Alds[row * KPAD + ((kt * 32 + lh * 8) ^ ((row & 7) << 3))];
        }
        #pragma unroll
        for (int g3 = 0; g3 < 3; ++g3)
            #pragma unroll
            for (int mf = 0; mf < 4; ++mf)
                acc[g3][mf] = __builtin_amdgcn_mfma_f32_16x16x32_bf16(
                    a[mf], b[g3], acc[g3][mf], 0, 0, 0);
    }
    // GEMM2: h_n plane only (A k-slice 128..256)
    #pragma unroll
    for (int kt = 0; kt < 4; ++kt) {
        short8v b2 = Bv2[(n8 * 4 + kt) * 64];
        short8v a[4];
        #pragma unroll
        for (int mf = 0; mf < 4; ++mf) {
            const int row = mf * 16 + lr;
            a[mf] = *(const short8v*)&Alds[row * KPAD + (((128 + kt * 32) + lh * 8) ^ ((row & 7) << 3))];
        }
        #pragma unroll
        for (int mf = 0; mf < 4; ++mf)
            acc[3][mf] = __builtin_amdgcn_mfma_f32_16x16x32_bf16(
                a[mf], b2, acc[3][mf], 0, 0, 0);
    }

    // ---- epilogue: compute o in regs (h from LDS), LDS-stage, coalesced stores ----
    const int c = n8 * 16 + lr;
    const float br = bih[c] + bhh[c];
    const float bz = bih[HDIM + c] + bhh[HDIM + c];
    const float bin = bih[2 * HDIM + c];
    const float bhn = bhh[2 * HDIM + c];
    const int hg = 16 + (c >> 3);        // 16B-group of element 128+c
    const int ho = c & 7;
    float o[4][4];
    #pragma unroll
    for (int mf = 0; mf < 4; ++mf)
        #pragma unroll
        for (int ii = 0; ii < 4; ++ii) {
            const int row = mf * 16 + lh * 4 + ii;
            const float h = bf2f(Alds[row * KPAD + (hg ^ (row & 7)) * 8 + ho]);
            const float r = sigmoidf_(acc[0][mf][ii] + br);
            const float z = sigmoidf_(acc[1][mf][ii] + bz);
            const float ng = tanhf_(acc[2][mf][ii] + bin + r * (acc[3][mf][ii] + bhn));
            o[mf][ii] = sh_has[row] ? (1.f - z) * ng + z * h : h;
        }
    __syncthreads();                      // all A/h reads done -> safe to reuse LDS
    float* o_lds = (float*)Alds;          // [64][OPITCH] = 33280 B, fits in Alds
    #pragma unroll
    for (int mf = 0; mf < 4; ++mf)
        #pragma unroll
        for (int ii = 0; ii < 4; ++ii) {
            const int row = mf * 16 + lh * 4 + ii;
            o_lds[row * OPITCH + c] = o[mf][ii];
        }
    __syncthreads();
    const int nvalid = (N_NODES - base < BM) ? (N_NODES - base) : BM;
    #pragma unroll
    for (int sw = 0; sw < 4; ++sw) {
        const int idx = sw * 2048 + tid * 4;      // float index in 64x128 tile
        const int row = idx >> 7, col = idx & 127;
        if (row < nvalid) {
            const float4 v = *(const float4*)&o_lds[row * OPITCH + col];
            *(float4*)&out[(size_t)(base + row) * HDIM + col] = v;
        }
    }
}

extern "C" void kernel_launch(void* const* d_in, const int* in_sizes, int n_in,
                              void* d_out, int out_size, void* d_ws, size_t ws_size,
                              hipStream_t stream) {
    const int* src       = (const int*)d_in[0];
    const int* dst       = (const int*)d_in[1];
    const float* edge_ts = (const float*)d_in[2];
    const float* ef      = (const float*)d_in[3];
    const float* mem     = (const float*)d_in[4];
    const float* lut     = (const float*)d_in[5];
    const float* tw      = (const float*)d_in[6];
    const float* tb      = (const float*)d_in[7];
    const float* Wih     = (const float*)d_in[8];
    const float* Whh     = (const float*)d_in[9];
    const float* bih     = (const float*)d_in[10];
    const float* bhh     = (const float*)d_in[11];
    float* out = (float*)d_out;

    char* ws = (char*)d_ws;
    unsigned long long* keys = (unsigned long long*)ws;      // 400000 B (region 512K)
    unsigned short* wbF1 = (unsigned short*)(ws + 524288);   // 393216 B
    unsigned short* wbF2 = (unsigned short*)(ws + 917504);   //  32768 B

    init_convert_kernel<<<KEYS_BLOCKS + CONV_BLOCKS, 256, 0, stream>>>(
        keys, Wih, Whh, wbF1, wbF2);
    scan_edges_kernel<<<(N_EDGES + 255) / 256, 256, 0, stream>>>(dst, edge_ts, keys);
    gru_mfma_kernel<<<NBLOCKS, NT, 0, stream>>>(
        src, edge_ts, ef, mem, lut, tw, tb, bih, bhh, wbF1, wbF2, keys, out);
}